// Round 3
// baseline (38505.338 us; speedup 1.0000x reference)
//
#include <hip/hip_runtime.h>
#include <stdint.h>
#include <stddef.h>

#define BB   128
#define TT   64
#define SDIM 64
#define DDET 2048
#define HHID 2048
#define AACT 64
#define OOBS 2048

// ---------------- threefry2x32 (JAX-compatible, 20 rounds) ----------------
__host__ __device__ inline uint32_t tf_rotl(uint32_t x, int r) {
  return (x << r) | (x >> (32 - r));
}

__host__ __device__ inline void tf2x32(uint32_t k0, uint32_t k1, uint32_t x0, uint32_t x1,
                                       uint32_t* o0, uint32_t* o1) {
  uint32_t ks2 = 0x1BD11BDAu ^ k0 ^ k1;
  x0 += k0; x1 += k1;
#define TFR(r) { x0 += x1; x1 = tf_rotl(x1, (r)); x1 ^= x0; }
  TFR(13) TFR(15) TFR(26) TFR(6)
  x0 += k1;  x1 += ks2 + 1u;
  TFR(17) TFR(29) TFR(16) TFR(24)
  x0 += ks2; x1 += k0 + 2u;
  TFR(13) TFR(15) TFR(26) TFR(6)
  x0 += k0;  x1 += k1 + 3u;
  TFR(17) TFR(29) TFR(16) TFR(24)
  x0 += k1;  x1 += ks2 + 4u;
  TFR(13) TFR(15) TFR(26) TFR(6)
  x0 += ks2; x1 += k0 + 5u;
#undef TFR
  *o0 = x0; *o1 = x1;
}

// ---------------- device math matching JAX/XLA lowerings ----------------
__device__ inline float eluf(float x)       { return x > 0.f ? x : expm1f(x); }
__device__ inline float sigmoidf_(float x)  { return 1.f / (1.f + expf(-x)); }
// jnp.logaddexp(x, 0) = max(x,0) + log1p(exp(-|x|))
__device__ inline float softplusf_(float x) { return fmaxf(x, 0.f) + log1pf(expf(-fabsf(x))); }

// XLA ErfInv32 (Giles polynomials)
__device__ inline float erfinv_xla(float x) {
  float w = -log1pf(-x * x);
  float p;
  if (w < 5.0f) {
    w = w - 2.5f;
    p = 2.81022636e-08f;
    p = 3.43273939e-07f + p * w;
    p = -3.5233877e-06f + p * w;
    p = -4.39150654e-06f + p * w;
    p = 0.00021858087f + p * w;
    p = -0.00125372503f + p * w;
    p = -0.00417768164f + p * w;
    p = 0.246640727f + p * w;
    p = 1.50140941f + p * w;
  } else {
    w = sqrtf(w) - 3.0f;
    p = -0.000200214257f;
    p = 0.000100950558f + p * w;
    p = 0.00134934322f + p * w;
    p = -0.00367342844f + p * w;
    p = 0.00573950773f + p * w;
    p = -0.0076224613f + p * w;
    p = 0.00943887047f + p * w;
    p = 1.00167406f + p * w;
    p = 2.83297682f + p * w;
  }
  return p * x;
}

// ---------------- generic multi-segment fp32 GEMM ----------------
// C[M=128, N] = epilogue( A0 @ W0 + A1 @ W1 + bias ), 64x64 tile, BK=32, 4x4 microtile.
// act: 0 = none, 1 = elu, 2 = sigmoid (+ optional rh=r*det write), 3 = GRU update epilogue
struct Seg {
  const float* A0; const float* W0;
  const float* A1; const float* W1;
  const float* bias; float* C;
  const float* E0; const float* E1;   // act2: E0=det(old); act3: E0=zr, E1=ax
  float* E2;                          // act2: rh output
  int lda0, ldw0, lda1, ldw1, K0, K1, ldc, act, writeT, blk0;
};
struct GemmPack { Seg s[3]; int nseg; };

__global__ __launch_bounds__(256) void gemm_ms(GemmPack P) {
  __shared__ float As[32][68];   // [k][m], padded
  __shared__ float Ws[32][64];   // [k][n]
  int bid = blockIdx.x;
  int si = 0;
  if (P.nseg > 1 && bid >= P.s[1].blk0) si = 1;
  if (P.nseg > 2 && bid >= P.s[2].blk0) si = 2;
  const Seg S = P.s[si];
  int local = bid - S.blk0;
  int m0 = (local & 1) << 6;     // 2 row-blocks (M=128)
  int n0 = (local >> 1) << 6;
  int tid = threadIdx.x;
  int tn4 = (tid & 15) << 2;
  int tm4 = (tid >> 4) << 2;
  int am  = tid >> 2;            // 0..63 (A stage row)
  int ak  = (tid & 3) << 2;      // 0,4,8,12 (A stage k)
  int wk  = tid >> 4;            // 0..15 (W stage k)
  int wn  = (tid & 15) << 2;     // W stage n

  float acc[4][4];
#pragma unroll
  for (int i = 0; i < 4; ++i)
#pragma unroll
    for (int j = 0; j < 4; ++j) acc[i][j] = 0.f;

  for (int pair = 0; pair < 2; ++pair) {
    const float* A; const float* W; int lda, ldw, K;
    if (pair == 0) { A = S.A0; W = S.W0; lda = S.lda0; ldw = S.ldw0; K = S.K0; }
    else {
      if (S.K1 <= 0) break;
      A = S.A1; W = S.W1; lda = S.lda1; ldw = S.ldw1; K = S.K1;
    }
    const float* Arow = A + (size_t)(m0 + am) * lda + ak;
    const float* Wrow = W + (size_t)wk * ldw + n0 + wn;
    for (int k0 = 0; k0 < K; k0 += 32) {
      float4 a0 = *(const float4*)(Arow + k0);
      float4 a1 = *(const float4*)(Arow + k0 + 16);
      float4 w0 = *(const float4*)(Wrow + (size_t)k0 * ldw);
      float4 w1 = *(const float4*)(Wrow + (size_t)(k0 + 16) * ldw);
      __syncthreads();
      As[ak + 0][am] = a0.x; As[ak + 1][am] = a0.y;
      As[ak + 2][am] = a0.z; As[ak + 3][am] = a0.w;
      As[ak + 16][am] = a1.x; As[ak + 17][am] = a1.y;
      As[ak + 18][am] = a1.z; As[ak + 19][am] = a1.w;
      *(float4*)&Ws[wk][wn]      = w0;
      *(float4*)&Ws[wk + 16][wn] = w1;
      __syncthreads();
#pragma unroll
      for (int k = 0; k < 32; ++k) {
        float4 av = *(const float4*)&As[k][tm4];
        float4 bv = *(const float4*)&Ws[k][tn4];
        acc[0][0] = fmaf(av.x, bv.x, acc[0][0]);
        acc[0][1] = fmaf(av.x, bv.y, acc[0][1]);
        acc[0][2] = fmaf(av.x, bv.z, acc[0][2]);
        acc[0][3] = fmaf(av.x, bv.w, acc[0][3]);
        acc[1][0] = fmaf(av.y, bv.x, acc[1][0]);
        acc[1][1] = fmaf(av.y, bv.y, acc[1][1]);
        acc[1][2] = fmaf(av.y, bv.z, acc[1][2]);
        acc[1][3] = fmaf(av.y, bv.w, acc[1][3]);
        acc[2][0] = fmaf(av.z, bv.x, acc[2][0]);
        acc[2][1] = fmaf(av.z, bv.y, acc[2][1]);
        acc[2][2] = fmaf(av.z, bv.z, acc[2][2]);
        acc[2][3] = fmaf(av.z, bv.w, acc[2][3]);
        acc[3][0] = fmaf(av.w, bv.x, acc[3][0]);
        acc[3][1] = fmaf(av.w, bv.y, acc[3][1]);
        acc[3][2] = fmaf(av.w, bv.z, acc[3][2]);
        acc[3][3] = fmaf(av.w, bv.w, acc[3][3]);
      }
    }
  }

#pragma unroll
  for (int i = 0; i < 4; ++i) {
    int m = m0 + tm4 + i;
    if (S.act == 3) {
      // det_new = (1-z)*h + z*tanh(ax + acc + b_a); C == det (in place)
      float o[4];
#pragma unroll
      for (int j = 0; j < 4; ++j) {
        int n = n0 + tn4 + j;
        float z   = S.E0[(size_t)m * (2 * DDET) + n];          // zr[:, :2048]
        float axv = S.E1[(size_t)m * DDET + n];
        float h   = S.C[(size_t)m * S.ldc + n];
        float a   = tanhf(axv + acc[i][j] + S.bias[n]);
        o[j] = (1.f - z) * h + z * a;
      }
      float4 st = make_float4(o[0], o[1], o[2], o[3]);
      *(float4*)(S.C + (size_t)m * S.ldc + n0 + tn4) = st;
      continue;
    }
    float v[4];
#pragma unroll
    for (int j = 0; j < 4; ++j) {
      float tv = acc[i][j];
      if (S.bias) tv += S.bias[n0 + tn4 + j];
      if (S.act == 1)      tv = eluf(tv);
      else if (S.act == 2) tv = sigmoidf_(tv);
      v[j] = tv;
    }
    if (!S.writeT) {
      float4 st = make_float4(v[0], v[1], v[2], v[3]);
      *(float4*)(S.C + (size_t)m * S.ldc + n0 + tn4) = st;
      if (S.act == 2 && S.E2 && n0 >= 2048) {
        // r-half tile: also write rh = r * det_old
        float4 hv = *(const float4*)(S.E0 + (size_t)m * DDET + (n0 - 2048) + tn4);
        float4 rh = make_float4(v[0] * hv.x, v[1] * hv.y, v[2] * hv.z, v[3] * hv.w);
        *(float4*)(S.E2 + (size_t)m * DDET + (n0 - 2048) + tn4) = rh;
      }
    } else {
#pragma unroll
      for (int j = 0; j < 4; ++j)
        S.C[(size_t)(n0 + tn4 + j) * S.ldc + m] = v[j];
    }
  }
}

// ---------------- S5: skinny heads, C[128 x 256] from transposed activations ----------------
__global__ __launch_bounds__(256) void s5_small(const float* __restrict__ x2T,
                                                const float* __restrict__ yT,
                                                const float* __restrict__ h3w,
                                                const float* __restrict__ zh2w,
                                                float* __restrict__ msum) {
  __shared__ float red[2][256];
  int bc = blockIdx.x;           // 0..127, 2 combined cols each
  int c0 = bc << 1;
  int tid = threadIdx.x;
  int b = tid & 127;
  int kh = tid >> 7;             // split K=2048 in two halves
  const float* AT; const float* W; int wc;
  if (c0 < 128) { AT = x2T; W = h3w;  wc = c0; }
  else          { AT = yT;  W = zh2w; wc = c0 - 128; }
  float s0 = 0.f, s1 = 0.f;
  int kbeg = kh << 10;
#pragma unroll 8
  for (int kk = 0; kk < 1024; ++kk) {
    int k = kbeg + kk;
    float a  = AT[(k << 7) + b];
    float w0 = W[(k << 7) + wc];
    float w1 = W[(k << 7) + wc + 1];
    s0 = fmaf(a, w0, s0);
    s1 = fmaf(a, w1, s1);
  }
  red[kh][b] = s0;
  red[kh][128 + b] = s1;
  __syncthreads();
  float v = red[0][tid & 255] + red[1][tid & 255];
  int cl = tid >> 7;
  int b2 = tid & 127;
  msum[(b2 << 8) + c0 + cl] = v;
}

// ---------------- S6: bias/softplus + threefry-normal sample + output writes ----------------
// RNG: JAX jax_threefry_partitionable=True (modern default) scheme:
//   bits[i] = o0 ^ o1 of threefry2x32(key, (0, i))  for i = b*64+s
__global__ __launch_bounds__(256) void s6_post(const float* __restrict__ msum,
                                               const float* __restrict__ h3b,
                                               const float* __restrict__ zh2b,
                                               const float* __restrict__ det,
                                               float* __restrict__ stoch,
                                               float* __restrict__ o_mh, float* __restrict__ o_sh,
                                               float* __restrict__ o_mz, float* __restrict__ o_sz,
                                               float* __restrict__ o_ft,
                                               int t, uint32_t k0, uint32_t k1) {
  int idx = blockIdx.x * 256 + threadIdx.x;     // 0 .. 128*2112-1
  int b = idx / 2112;
  int c = idx - b * 2112;
  size_t ftoff = (size_t)b * TT * 2112 + (size_t)t * 2112 + c;
  if (c >= 64) {                                 // feat[:, 64:] = det
    o_ft[ftoff] = det[(b << 11) + (c - 64)];
    return;
  }
  int s = c;
  float mh  = msum[(b << 8) + s]       + h3b[s];
  float shr = msum[(b << 8) + 64 + s]  + h3b[64 + s];
  float mz  = msum[(b << 8) + 128 + s] + zh2b[s];
  float szr = msum[(b << 8) + 192 + s] + zh2b[64 + s];
  float sh = softplusf_(shr) + 0.1f;
  float sz = softplusf_(szr) + 0.1f;

  // partitionable threefry random bits: per-element 64-bit counter (0, j)
  int j = (b << 6) + s;
  uint32_t r0, r1;
  tf2x32(k0, k1, 0u, (uint32_t)j, &r0, &r1);
  uint32_t bits = r0 ^ r1;

  float u01 = __uint_as_float((bits >> 9) | 0x3f800000u) - 1.0f;   // [0,1)
  const float LO = -0.99999994f;                 // nextafter(-1,0) in f32
  // (hi - lo) rounds to exactly 2.0f in f32; mul by 2 is exact
  float u = fmaxf(LO, __fadd_rn(__fmul_rn(u01, 2.0f), LO));
  float nrm = 1.41421356f * erfinv_xla(u);       // f32(sqrt(2)) * erfinv
  float sample = mz + sz * nrm;

  int ob = ((b * TT) + t) * SDIM + s;
  o_mh[ob] = mh; o_sh[ob] = sh; o_mz[ob] = mz; o_sz[ob] = sz;
  o_ft[ftoff] = sample;
  stoch[j] = sample;
}

// ---------------- zero init for carry (stoch, det) ----------------
__global__ __launch_bounds__(256) void zero_f4(float4* __restrict__ p) {
  int i = blockIdx.x * 256 + threadIdx.x;
  p[i] = make_float4(0.f, 0.f, 0.f, 0.f);
}

// ---------------- host ----------------
extern "C" void kernel_launch(void* const* d_in, const int* in_sizes, int n_in,
                              void* d_out, int out_size, void* d_ws, size_t ws_size,
                              hipStream_t stream) {
  (void)in_sizes; (void)n_in; (void)out_size; (void)ws_size;
  const float* obss    = (const float*)d_in[0];
  const float* actions = (const float*)d_in[1];
  const float* h1_w    = (const float*)d_in[2];
  const float* h1_b    = (const float*)d_in[3];
  const float* gru_wi  = (const float*)d_in[4];
  const float* gru_wh  = (const float*)d_in[5];
  const float* gru_b   = (const float*)d_in[6];
  const float* h2_w    = (const float*)d_in[7];
  const float* h2_b    = (const float*)d_in[8];
  const float* h3_w    = (const float*)d_in[9];
  const float* h3_b    = (const float*)d_in[10];
  const float* z_h1_w  = (const float*)d_in[11];
  const float* z_h1_b  = (const float*)d_in[12];
  const float* z_h2_w  = (const float*)d_in[13];
  const float* z_h2_b  = (const float*)d_in[14];

  float* out_mh = (float*)d_out;
  float* out_sh = out_mh + (size_t)BB * TT * SDIM;
  float* out_mz = out_sh + (size_t)BB * TT * SDIM;
  float* out_sz = out_mz + (size_t)BB * TT * SDIM;
  float* out_ft = out_sz + (size_t)BB * TT * SDIM;

  float* ws    = (float*)d_ws;
  float* stoch = ws;                         // 128*64
  float* det   = stoch + BB * SDIM;          // 128*2048
  float* x     = det + BB * DDET;            // 128*2048
  float* zr    = x + BB * DDET;              // 128*4096 (post-sigmoid z|r)
  float* ax    = zr + BB * 2 * DDET;         // 128*2048
  float* rh    = ax + BB * DDET;             // 128*2048 (r * det_old)
  float* x2T   = rh + BB * DDET;             // 2048*128 (transposed)
  float* yT    = x2T + (size_t)HHID * BB;    // 2048*128
  float* msum  = yT + (size_t)HHID * BB;     // 128*256

  // zero carry (harness poisons ws with 0xAA)
  int zn4 = (BB * SDIM + BB * DDET) / 4;     // 67584 float4 -> 264 blocks
  zero_f4<<<zn4 / 256, 256, 0, stream>>>((float4*)stoch);

  // host-side per-step keys, partitionable ("foldlike") split:
  //   split(key(42), 128)[j] = threefry2x32((0,42), (0, j))  (both output words)
  //   step t uses kk[1] = split[2t+1]
  uint32_t kk0[TT], kk1[TT];
  for (int t = 0; t < TT; ++t) {
    uint32_t o0, o1;
    tf2x32(0u, 42u, 0u, (uint32_t)(2 * t + 1), &o0, &o1);
    kk0[t] = o0; kk1[t] = o1;
  }

  for (int t = 0; t < TT; ++t) {
    // S1: x = elu([action|stoch] @ h1_w + h1_b)   (64 blocks)
    GemmPack p1{}; p1.nseg = 1;
    p1.s[0] = Seg{ actions + (size_t)t * AACT, h1_w,
                   stoch, h1_w + (size_t)AACT * DDET,
                   h1_b, x, nullptr, nullptr, nullptr,
                   TT * AACT, DDET, SDIM, DDET, AACT, SDIM, DDET, 1, 0, 0 };
    gemm_ms<<<2 * (DDET / 64), 256, 0, stream>>>(p1);

    // S2: zr = sigmoid(x@Wi_zr + det@Wh_zr + b_zr) [+ rh = r*det]; ax = x@Wi_a
    GemmPack p2{}; p2.nseg = 2;
    p2.s[0] = Seg{ x, gru_wi, det, gru_wh, gru_b, zr, det, nullptr, rh,
                   DDET, 3 * DDET, DDET, 3 * DDET, DDET, DDET, 2 * DDET, 2, 0, 0 };
    p2.s[1] = Seg{ x, gru_wi + 2 * DDET, nullptr, nullptr, nullptr, ax, nullptr, nullptr, nullptr,
                   DDET, 3 * DDET, 0, 0, DDET, 0, DDET, 0, 0, 128 };
    gemm_ms<<<192, 256, 0, stream>>>(p2);

    // S3: det = (1-z)*det + z*tanh(ax + rh@Wh_a + b_a)   (GRU epilogue, in-place det)
    GemmPack p3{}; p3.nseg = 1;
    p3.s[0] = Seg{ rh, gru_wh + 2 * DDET, nullptr, nullptr, gru_b + 2 * DDET, det, zr, ax, nullptr,
                   DDET, 3 * DDET, 0, 0, DDET, 0, DDET, 3, 0, 0 };
    gemm_ms<<<64, 256, 0, stream>>>(p3);

    // S4: x2T = elu(det@h2_w + b)^T ; yT = elu([det|ob]@z_h1_w + b)^T
    GemmPack p4{}; p4.nseg = 2;
    p4.s[0] = Seg{ det, h2_w, nullptr, nullptr, h2_b, x2T, nullptr, nullptr, nullptr,
                   DDET, HHID, 0, 0, DDET, 0, BB, 1, 1, 0 };
    p4.s[1] = Seg{ det, z_h1_w, obss + (size_t)t * OOBS, z_h1_w + (size_t)DDET * HHID,
                   z_h1_b, yT, nullptr, nullptr, nullptr,
                   DDET, HHID, TT * OOBS, HHID, DDET, OOBS, BB, 1, 1, 64 };
    gemm_ms<<<128, 256, 0, stream>>>(p4);

    // S5: msum[128 x 256] = [x2@h3_w | y@z_h2_w] (bias added in S6)
    s5_small<<<128, 256, 0, stream>>>(x2T, yT, h3_w, z_h2_w, msum);

    // S6: softplus heads, threefry-normal sample_z, write outputs + stoch
    s6_post<<<(BB * 2112) / 256, 256, 0, stream>>>(msum, h3_b, z_h2_b, det, stoch,
                                                   out_mh, out_sh, out_mz, out_sz, out_ft,
                                                   t, kk0[t], kk1[t]);
  }
}